// Round 1
// baseline (512.795 us; speedup 1.0000x reference)
//
#include <hip/hip_runtime.h>

// Problem: B=256, N=131072, F=16. Two-pass causal FIR with masking:
//   v[i] = (i>=16) ? x[i] + sum_{j<16} h[j]*x[i-1-j] : 0
//   y[i] = (i>=16) ? v[i] + sum_{j<16} h[15-j]*v[i-1-j] : 0
// For i >= 32, y = 33-tap conv with g = conv([1,h], [1,reverse(h)]).
// i in [16,32) handled explicitly; i < 16 is zero.
//
// R2 -> R3 theory: R2 measured 247.6us = 1.08 TB/s = 17% of achievable HBM
// (roofline 43us). Suspects: (1) stores still per-lane 64B-strided (the same
// pathology R1->R2 fixed for loads), (2) ~97 live floats -> ~130 VGPR -> 3
// waves/SIMD, (3) 48 scalar ds_read_b32 per thread.
// R3: lane-interleaved output ownership. Thread t, group k owns outputs
// i0 + 1024k + 4t + {0..3}:
//   - stores: lane-contiguous float4 -> fully coalesced (1KB/wave-inst)
//   - LDS: linear (unpadded) tile, window = 9x ds_read_b128, lane stride 16B
//   - regs: gg[33]+w[36]+o[4] ~ 75 live -> ~5 waves/SIMD
// g computed per-block into LDS behind the staging barrier (kills the second
// kernel launch and the 33 uniform global loads per thread).

#define NROW 131072
#define TILE 4096
#define HALO 32

__global__ __launch_bounds__(256, 4) void fir2_kernel(const float* __restrict__ x,
                                                      const float* __restrict__ h,
                                                      float* __restrict__ y) {
    __shared__ __align__(16) float lds[TILE + HALO];   // lds[j] = x[i0 - 32 + j]
    __shared__ __align__(16) float gsh[36];            // g[0..32], padded

    const int bid = blockIdx.x;
    const int row = bid >> 5;   // 32 chunks per row
    const int chunk = bid & 31;
    const int i0 = chunk * TILE;
    const int t = (int)threadIdx.x;
    const float* __restrict__ xr = x + (size_t)row * NROW;
    float* __restrict__ yr = y + (size_t)row * NROW;

    // ---- g = conv([1,h],[1,rev(h)]), computed per block (h is L1/L2-hot) ----
    if (t < 33) {
        float s = 0.f;
#pragma unroll
        for (int a = 0; a <= 16; ++a) {
            const int b = t - a;
            if (b >= 0 && b <= 16) {
                const float ka = (a == 0) ? 1.f : h[a - 1];
                const float kb = (b == 0) ? 1.f : h[16 - b];
                s += ka * kb;
            }
        }
        gsh[t] = s;
    }

    // ---- Stage tile [i0-32, i0+4096) into linear LDS, coalesced float4 ----
    const int base = i0 - HALO;
#pragma unroll
    for (int k = 0; k < 4; ++k) {
        const int f = t + 256 * k;          // float4 index within tile
        const int gidx = base + 4 * f;      // global float index
        float4 v = make_float4(0.f, 0.f, 0.f, 0.f);
        if (gidx >= 0) v = *(const float4*)(xr + gidx);   // neg only chunk0,k0,t<8
        *(float4*)(lds + 4 * f) = v;
    }
    if (t < 8) {                            // halo tail: float4 1024..1031
        const int f = 1024 + t;
        float4 v = *(const float4*)(xr + base + 4 * f);   // always in-bounds
        *(float4*)(lds + 4 * f) = v;
    }
    __syncthreads();

    float gg[33];
#pragma unroll
    for (int m = 0; m < 33; ++m) gg[m] = gsh[m];   // LDS broadcast reads

    // ---- 4 groups; group k: outputs p = i0 + 1024k + 4t + {0..3} ----
#pragma unroll 1
    for (int k = 0; k < 4; ++k) {
        const int jb = 1024 * k + 4 * t;    // window start: x[p0 - 32] at lds[jb]
        float w[36];
#pragma unroll
        for (int q = 0; q < 9; ++q) {
            const float4 v = *(const float4*)(lds + jb + 4 * q);  // b128, coalesced
            w[4 * q + 0] = v.x; w[4 * q + 1] = v.y;
            w[4 * q + 2] = v.z; w[4 * q + 3] = v.w;
        }
        float o[4];
#pragma unroll
        for (int c = 0; c < 4; ++c) {
            float s = 0.f;
#pragma unroll
            for (int m = 0; m < 33; ++m) s += gg[m] * w[c + 32 - m];
            o[c] = s;
        }

        // ---- boundary fixup: outputs [0,32), only chunk 0 / group 0 / t<8 ----
        if (chunk == 0 && k == 0 && t < 8) {
#pragma unroll
            for (int c = 0; c < 4; ++c)
                if (4 * t + c < 16) o[c] = 0.f;          // y[i<16] = 0
            if (t >= 4) {                                 // outputs 16..31
                // v[16+u] = x[16+u] + sum_j h[j] x[15+u-j]; x[i] = lds[i+32] here
                float vloc[16];
#pragma unroll
                for (int u = 0; u < 16; ++u) {
                    const int p = 16 + u;
                    float s = lds[p + 32];
#pragma unroll
                    for (int j = 0; j < 16; ++j) s += h[j] * lds[p + 31 - j];
                    vloc[u] = s;
                }
                // y[p] = v[p] + sum_{j<=p-17} h[15-j] v[p-1-j]; all static idx
#pragma unroll
                for (int p = 16; p < 32; ++p) {
                    float s = vloc[p - 16];
#pragma unroll
                    for (int j = 0; j < 16; ++j)
                        if (j <= p - 17) s += h[15 - j] * vloc[p - 17 - j];
                    if ((p >> 2) == t) o[p & 3] = s;     // static reg index
                }
            }
        }

        *(float4*)(yr + i0 + jb) = make_float4(o[0], o[1], o[2], o[3]);  // coalesced
    }
}

extern "C" void kernel_launch(void* const* d_in, const int* in_sizes, int n_in,
                              void* d_out, int out_size, void* d_ws, size_t ws_size,
                              hipStream_t stream) {
    const float* x = (const float*)d_in[0];   // (256, 131072) fp32
    const float* h = (const float*)d_in[1];   // (1, 16) fp32
    float* y = (float*)d_out;                 // (256, 131072) fp32
    (void)d_ws; (void)ws_size;

    fir2_kernel<<<8192, 256, 0, stream>>>(x, h, y);
}

// Round 4
// 236.907 us; speedup vs baseline: 2.1645x; 2.1645x over previous
//
#include <hip/hip_runtime.h>

// Problem: B=256, N=131072, F=16. Two-pass causal FIR with masking:
//   v[i] = (i>=16) ? x[i] + sum_{j<16} h[j]*x[i-1-j] : 0
//   y[i] = (i>=16) ? v[i] + sum_{j<16} h[15-j]*v[i-1-j] : 0
// For i >= 32, y = 33-tap conv with g = conv([1,h],[1,rev(h)]).
// i in [16,32) handled explicitly; i < 16 zero.
//
// R3 -> R4: R3 spilled (VGPR_Count=64 vs ~90 live floats) -> 1.39 GB of
// scratch writes (WRITE_SIZE 1.49 GB vs 134 MB output), dur 366us, VALU 9%.
// Fixes:
//  - g[33] via workspace + uniform-index loads -> SGPRs; hot-path live
//    VGPRs ~50. No launch_bounds occupancy clamp.
//  - LDS pad: +4 floats per 32 (16B per 128B stripe). b128 blocks never
//    cross a pad; lane->bank map becomes a rotating diagonal -> conflict-free.
//  - Non-temporal y stores: y never re-read; keeps x L3-resident (134 MB
//    < 256 MB L3), so steady-state HBM traffic ~= writes only.
//  - Boundary fixup as cold post-loop overwrite, all-static reg indexing.
// R4 -> R5: compile fix — __builtin_nontemporal_store needs a native clang
// vector type (ext_vector_type(4)), not HIP_vector_type<float,4>.
// R5 -> R6: resubmit unchanged (R5 bench was an infra failure, kernel never ran).

#define NROW 131072
#define TILE 4096
#define HALO 32
// float index j -> padded LDS index: +4 floats per 32
#define PADIDX(j) ((j) + ((((j) >> 5)) << 2))
#define LDS_FLOATS (PADIDX(TILE + HALO - 1) + 1)   // 4127 + 512 + 1 = 4640

typedef float f32x4 __attribute__((ext_vector_type(4)));

__global__ void compute_g_kernel(const float* __restrict__ h, float* __restrict__ g) {
    int m = threadIdx.x;
    if (m < 33) {
        float s = 0.f;
#pragma unroll
        for (int a = 0; a <= 16; ++a) {
            int b = m - a;
            if (b >= 0 && b <= 16) {
                float ka = (a == 0) ? 1.f : h[a - 1];
                float kb = (b == 0) ? 1.f : h[16 - b];
                s += ka * kb;
            }
        }
        g[m] = s;
    }
}

__global__ __launch_bounds__(256) void fir2_kernel(const float* __restrict__ x,
                                                   const float* __restrict__ g,
                                                   const float* __restrict__ h,
                                                   float* __restrict__ y) {
    __shared__ __align__(16) float lds[LDS_FLOATS];

    const int bid = blockIdx.x;
    const int row = bid >> 5;   // 32 chunks per row
    const int chunk = bid & 31;
    const int i0 = chunk * TILE;
    const int t = (int)threadIdx.x;
    const float* __restrict__ xr = x + (size_t)row * NROW;
    float* __restrict__ yr = y + (size_t)row * NROW;

    // ---- g[0..32]: uniform indices off a uniform pointer -> s_load (SGPRs) ----
    float gg[33];
#pragma unroll
    for (int m = 0; m < 33; ++m) gg[m] = g[m];

    // ---- Stage tile [i0-32, i0+4096) into padded LDS, coalesced float4 ----
    const int base = i0 - HALO;
#pragma unroll
    for (int k = 0; k < 4; ++k) {
        const int f = t + 256 * k;          // float4 index within tile
        const int gidx = base + 4 * f;      // global float index
        f32x4 v = (f32x4)(0.f);
        if (gidx >= 0) v = *(const f32x4*)(xr + gidx);    // neg only chunk0,k0,t<8
        *(f32x4*)(lds + PADIDX(4 * f)) = v;               // 4f..4f+3 same stripe
    }
    if (t < 8) {                            // halo tail: float4 1024..1031
        const int f = 1024 + t;
        f32x4 v = *(const f32x4*)(xr + base + 4 * f);     // always in-bounds
        *(f32x4*)(lds + PADIDX(4 * f)) = v;
    }
    __syncthreads();

    // ---- 4 groups; group k: outputs p = i0 + 1024k + 4t + {0..3} ----
#pragma unroll 1
    for (int k = 0; k < 4; ++k) {
        const int jb = 1024 * k + 4 * t;    // window start: x[p0-32] at lds idx jb
        float w[36];
#pragma unroll
        for (int q = 0; q < 9; ++q) {       // 9x ds_read_b128, diagonalized banks
            const f32x4 v = *(const f32x4*)(lds + PADIDX(jb + 4 * q));
            w[4 * q + 0] = v.x; w[4 * q + 1] = v.y;
            w[4 * q + 2] = v.z; w[4 * q + 3] = v.w;
        }
        f32x4 o;
#pragma unroll
        for (int c = 0; c < 4; ++c) {
            float s = 0.f;
#pragma unroll
            for (int m = 0; m < 33; ++m) s = fmaf(gg[m], w[c + 32 - m], s);
            o[c] = s;
        }
        // y never re-read: nt store keeps x L3-resident
        __builtin_nontemporal_store(o, (f32x4*)(yr + i0 + jb));
    }

    // ---- Cold boundary fixup: outputs [0,32), chunk 0 only, lanes 0..7 ----
    if (chunk == 0 && t < 8) {
        f32x4 o = (f32x4)(0.f);
        if (t >= 4) {
            float hh[16];
#pragma unroll
            for (int j = 0; j < 16; ++j) hh[j] = h[j];   // uniform -> s_load
            // v[16+u] = x[16+u] + sum_j h[j] x[15+u-j];  x[i] = lds[PADIDX(i+32)]
            float vloc[16];
#pragma unroll
            for (int u = 0; u < 16; ++u) {
                const int p = 16 + u;
                float s = lds[PADIDX(p + 32)];
#pragma unroll
                for (int j = 0; j < 16; ++j)
                    s = fmaf(hh[j], lds[PADIDX(p + 31 - j)], s);
                vloc[u] = s;
            }
            // y[p] = v[p] + sum_{j<=p-17} h[15-j] v[p-1-j]; all static indexing
#pragma unroll
            for (int p = 16; p < 32; ++p) {
                float s = vloc[p - 16];
#pragma unroll
                for (int j = 0; j < 16; ++j)
                    if (j <= p - 17) s = fmaf(hh[15 - j], vloc[p - 17 - j], s);
                if ((p >> 2) == t) o[p & 3] = s;         // static reg index
            }
        }
        __builtin_nontemporal_store(o, (f32x4*)(yr + 4 * t));  // overwrites k=0 store
    }
}

extern "C" void kernel_launch(void* const* d_in, const int* in_sizes, int n_in,
                              void* d_out, int out_size, void* d_ws, size_t ws_size,
                              hipStream_t stream) {
    const float* x = (const float*)d_in[0];   // (256, 131072) fp32
    const float* h = (const float*)d_in[1];   // (1, 16) fp32
    float* y = (float*)d_out;                 // (256, 131072) fp32
    float* g = (float*)d_ws;                  // 33 floats of scratch
    (void)in_sizes; (void)n_in; (void)out_size; (void)ws_size;

    compute_g_kernel<<<1, 64, 0, stream>>>(h, g);
    fir2_kernel<<<8192, 256, 0, stream>>>(x, g, h, y);
}